// Round 1
// baseline (1617.037 us; speedup 1.0000x reference)
//
#include <hip/hip_runtime.h>
#include <math.h>

// LSD (local shape descriptors), 128^3, 8 labels, sigma=5, truncate=3 -> 31-tap kernel.
//
// Algebra: for label mask m, define G_{abc} = (k_a *_z)(k_b *_y)(k_c *_x) m with
//   k0(u)=w(u), k1(u)=u w(u), k2(u)=u^2 w(u)  (w = normalized gaussian).
// Then at a voxel with mass=G000>0, p=G100/mass, q=G010/mass, s=G001/mass:
//   mean_offset = 0.5 - {p,q,s}/(2 sigma)
//   cov: zz=(G200/mass - p^2)/s2, yy=(G020/mass - q^2)/s2, xx=(G002/mass - s^2)/s2,
//        zy=(G110/mass - pq)/s2, yx=(G011/mass - qs)/s2, zx=(G101/mass - ps)/s2
// All translation-invariant: coords input is not needed at all.
// Output voxel v takes the descriptor of its own label seg[v] (masks disjoint).

constexpr int NV = 128 * 128 * 128;   // 2,097,152 voxels
constexpr int SLICE = 128 * 128;      // 16384
constexpr int R = 15;                 // truncate*sigma + 0.5 = 15
constexpr int KL = 31;                // kernel taps

struct Kw { float k0[KL]; float k1[KL]; float k2[KL]; };

// Pass 1: conv along z of the label indicator with k0,k1,k2 -> A[0..2]
__global__ __launch_bounds__(256) void pass_z(const int* __restrict__ seg,
                                              float* __restrict__ A,
                                              int label, Kw kw) {
    const int v = blockIdx.x * 256 + threadIdx.x;
    const int z = v >> 14;                    // block-uniform (256 | 16384)
    float a0 = 0.f, a1 = 0.f, a2 = 0.f;
    for (int j = 0; j < KL; ++j) {
        int zz = z + j - R;
        if ((unsigned)zz < 128u) {
            float m = (seg[v + (j - R) * SLICE] == label) ? 1.f : 0.f;
            a0 = fmaf(kw.k0[j], m, a0);
            a1 = fmaf(kw.k1[j], m, a1);
            a2 = fmaf(kw.k2[j], m, a2);
        }
    }
    A[v] = a0; A[NV + v] = a1; A[2 * NV + v] = a2;
}

// Pass 2: conv along y; (z-order,y-order): B00,B01,B02,B10,B11,B20
__global__ __launch_bounds__(256) void pass_y(const float* __restrict__ A,
                                              float* __restrict__ B, Kw kw) {
    const int v = blockIdx.x * 256 + threadIdx.x;
    const int y = (v >> 7) & 127;
    float b00 = 0, b01 = 0, b02 = 0, b10 = 0, b11 = 0, b20 = 0;
    for (int j = 0; j < KL; ++j) {
        int yy = y + j - R;
        if ((unsigned)yy < 128u) {
            int idx = v + (j - R) * 128;
            float a0 = A[idx], a1 = A[NV + idx], a2 = A[2 * NV + idx];
            float w0 = kw.k0[j], w1 = kw.k1[j], w2 = kw.k2[j];
            b00 = fmaf(w0, a0, b00);
            b01 = fmaf(w1, a0, b01);
            b02 = fmaf(w2, a0, b02);
            b10 = fmaf(w0, a1, b10);
            b11 = fmaf(w1, a1, b11);
            b20 = fmaf(w0, a2, b20);
        }
    }
    B[v] = b00; B[NV + v] = b01; B[2 * NV + v] = b02;
    B[3 * NV + v] = b10; B[4 * NV + v] = b11; B[5 * NV + v] = b20;
}

// Pass 3: conv along x fused with descriptor epilogue (masked write).
__global__ __launch_bounds__(256) void pass_x_combine(const float* __restrict__ B,
                                                      const int* __restrict__ seg,
                                                      float* __restrict__ out,
                                                      int label, Kw kw) {
    const int v = blockIdx.x * 256 + threadIdx.x;
    const int x = v & 127;
    float g000 = 0, g001 = 0, g002 = 0, g010 = 0, g011 = 0,
          g020 = 0, g100 = 0, g101 = 0, g110 = 0, g200 = 0;
    for (int j = 0; j < KL; ++j) {
        int xx = x + j - R;
        if ((unsigned)xx < 128u) {
            int idx = v + (j - R);
            float b00 = B[idx],          b01 = B[NV + idx],     b02 = B[2 * NV + idx],
                  b10 = B[3 * NV + idx], b11 = B[4 * NV + idx], b20 = B[5 * NV + idx];
            float w0 = kw.k0[j], w1 = kw.k1[j], w2 = kw.k2[j];
            g000 = fmaf(w0, b00, g000);
            g001 = fmaf(w1, b00, g001);
            g002 = fmaf(w2, b00, g002);
            g010 = fmaf(w0, b01, g010);
            g011 = fmaf(w1, b01, g011);
            g020 = fmaf(w0, b02, g020);
            g100 = fmaf(w0, b10, g100);
            g101 = fmaf(w1, b10, g101);
            g110 = fmaf(w0, b11, g110);
            g200 = fmaf(w0, b20, g200);
        }
    }
    if (seg[v] == label) {
        float denom = (g000 > 0.f) ? g000 : 1.f;
        float inv = 1.f / denom;
        float p = g100 * inv, q = g010 * inv, s = g001 * inv;
        const float cs = 1.0f / 25.0f;   // 1/sigma^2
        float o[10];
        o[0] = 0.5f - 0.1f * p;          // 1/(2 sigma) = 0.1
        o[1] = 0.5f - 0.1f * q;
        o[2] = 0.5f - 0.1f * s;
        o[3] = (g200 * inv - p * p) * cs;
        o[4] = (g020 * inv - q * q) * cs;
        o[5] = (g002 * inv - s * s) * cs;
        o[6] = (g110 * inv - p * q) * cs;
        o[7] = (g011 * inv - q * s) * cs;
        o[8] = (g101 * inv - p * s) * cs;
        o[9] = g000;                     // mass
#pragma unroll
        for (int c = 0; c < 10; ++c) {
            float val = fminf(fmaxf(o[c], 0.f), 1.f);
            out[c * NV + v] = val;
        }
    }
}

extern "C" void kernel_launch(void* const* d_in, const int* in_sizes, int n_in,
                              void* d_out, int out_size, void* d_ws, size_t ws_size,
                              hipStream_t stream) {
    const int* seg = (const int*)d_in[0];
    // d_in[1] (coords) is unused: math is translation-invariant (see header comment).
    float* out = (float*)d_out;
    float* A = (float*)d_ws;                  // 3 volumes
    float* B = A + (size_t)3 * NV;            // 6 volumes  (total 9*8MB = 72MB scratch)

    // Build moment kernels on host; passed by value (372 B kernarg).
    Kw kw;
    double g[KL], S = 0.0;
    for (int j = 0; j < KL; ++j) { double d = j - R; g[j] = exp(-0.5 * d * d / 25.0); S += g[j]; }
    for (int j = 0; j < KL; ++j) {
        double gn = g[j] / S, d = j - R;
        kw.k0[j] = (float)gn;
        kw.k1[j] = (float)(-d * gn);   // conv kernel k1 evaluated at (Z - t) = -d
        kw.k2[j] = (float)(d * d * gn);
    }

    // Unlabeled (seg==0) voxels must be 0; combine writes only masked voxels.
    hipMemsetAsync(d_out, 0, (size_t)out_size * sizeof(float), stream);

    dim3 grid(NV / 256), block(256);
    for (int label = 1; label <= 8; ++label) {
        pass_z<<<grid, block, 0, stream>>>(seg, A, label, kw);
        pass_y<<<grid, block, 0, stream>>>(A, B, kw);
        pass_x_combine<<<grid, block, 0, stream>>>(B, seg, out, label, kw);
    }
}

// Round 2
// 1363.656 us; speedup vs baseline: 1.1858x; 1.1858x over previous
//
#include <hip/hip_runtime.h>
#include <math.h>

// LSD (local shape descriptors), 128^3, 8 labels, sigma=5, truncate=3 -> 31-tap kernel.
//
// Algebra: for label mask m, define G_{abc} = (k_a *_z)(k_b *_y)(k_c *_x) m with
//   k0(u)=w(u), k1(u)=u w(u), k2(u)=u^2 w(u)  (w = normalized gaussian).
// Then at a voxel with mass=G000>0, p=G100/mass, q=G010/mass, s=G001/mass:
//   mean_offset = 0.5 - {p,q,s}/(2 sigma)
//   cov: zz=(G200/mass - p^2)/s2, ..., zy=(G110/mass - pq)/s2, ...
// Translation-invariant: coords input not needed. Masks disjoint -> each voxel
// takes only its own label's descriptor (no accumulation).
//
// R1: XCD z-slab swizzle. Measured 7.25x FETCH overfetch in pass_y (174 MB vs
// 24 MB ideal): consecutive blocks share 30/31 input rows but land on different
// XCDs (round-robin %8), whose L2s are disjoint. Remap blockIdx so XCD g=h&7
// owns z in [g*16,(g+1)*16): slab working set ~3 MB fits 4 MB per-XCD L2.
// y-conv and x-conv never cross slices; z-conv halo (+-15 slices) still fits.

constexpr int NV = 128 * 128 * 128;   // 2,097,152 voxels
constexpr int SLICE = 128 * 128;      // 16384
constexpr int R = 15;                 // truncate*sigma + 0.5 = 15
constexpr int KL = 31;                // kernel taps

struct Kw { float k0[KL]; float k1[KL]; float k2[KL]; };

// grid is always 8192 blocks of 256. XCD g = h&7 gets logical slab g:
// logical block l in [g*1024, (g+1)*1024) -> z in [g*16, (g+1)*16).
__device__ __forceinline__ int swz(int h) { return (h & 7) * 1024 + (h >> 3); }

__global__ __launch_bounds__(256) void seg_to_u8(const int* __restrict__ seg,
                                                 unsigned char* __restrict__ seg8) {
    const int t = blockIdx.x * 256 + threadIdx.x;     // 2048 blocks: t < 512K
    const int4 s = ((const int4*)seg)[t];
    uchar4 u = make_uchar4((unsigned char)s.x, (unsigned char)s.y,
                           (unsigned char)s.z, (unsigned char)s.w);
    ((uchar4*)seg8)[t] = u;
}

// Pass 1: conv along z of the label indicator with k0,k1,k2 -> A[0..2]
__global__ __launch_bounds__(256) void pass_z8(const unsigned char* __restrict__ seg8,
                                               float* __restrict__ A,
                                               int label, Kw kw) {
    const int v = swz(blockIdx.x) * 256 + threadIdx.x;
    const int z = v >> 14;                    // block-uniform
    const unsigned char lab = (unsigned char)label;
    float a0 = 0.f, a1 = 0.f, a2 = 0.f;
    for (int j = 0; j < KL; ++j) {
        int zz = z + j - R;
        if ((unsigned)zz < 128u) {
            float m = (seg8[v + (j - R) * SLICE] == lab) ? 1.f : 0.f;
            a0 = fmaf(kw.k0[j], m, a0);
            a1 = fmaf(kw.k1[j], m, a1);
            a2 = fmaf(kw.k2[j], m, a2);
        }
    }
    A[v] = a0; A[NV + v] = a1; A[2 * NV + v] = a2;
}

__global__ __launch_bounds__(256) void pass_z32(const int* __restrict__ seg,
                                                float* __restrict__ A,
                                                int label, Kw kw) {
    const int v = swz(blockIdx.x) * 256 + threadIdx.x;
    const int z = v >> 14;
    float a0 = 0.f, a1 = 0.f, a2 = 0.f;
    for (int j = 0; j < KL; ++j) {
        int zz = z + j - R;
        if ((unsigned)zz < 128u) {
            float m = (seg[v + (j - R) * SLICE] == label) ? 1.f : 0.f;
            a0 = fmaf(kw.k0[j], m, a0);
            a1 = fmaf(kw.k1[j], m, a1);
            a2 = fmaf(kw.k2[j], m, a2);
        }
    }
    A[v] = a0; A[NV + v] = a1; A[2 * NV + v] = a2;
}

// Pass 2: conv along y; outputs (z-order,y-order): B00,B01,B02,B10,B11,B20
__global__ __launch_bounds__(256) void pass_y(const float* __restrict__ A,
                                              float* __restrict__ B, Kw kw) {
    const int v = swz(blockIdx.x) * 256 + threadIdx.x;
    const int y = (v >> 7) & 127;
    float b00 = 0, b01 = 0, b02 = 0, b10 = 0, b11 = 0, b20 = 0;
    for (int j = 0; j < KL; ++j) {
        int yy = y + j - R;
        if ((unsigned)yy < 128u) {
            int idx = v + (j - R) * 128;
            float a0 = A[idx], a1 = A[NV + idx], a2 = A[2 * NV + idx];
            float w0 = kw.k0[j], w1 = kw.k1[j], w2 = kw.k2[j];
            b00 = fmaf(w0, a0, b00);
            b01 = fmaf(w1, a0, b01);
            b02 = fmaf(w2, a0, b02);
            b10 = fmaf(w0, a1, b10);
            b11 = fmaf(w1, a1, b11);
            b20 = fmaf(w0, a2, b20);
        }
    }
    B[v] = b00; B[NV + v] = b01; B[2 * NV + v] = b02;
    B[3 * NV + v] = b10; B[4 * NV + v] = b11; B[5 * NV + v] = b20;
}

// Pass 3: conv along x fused with descriptor epilogue (masked write).
__global__ __launch_bounds__(256) void pass_x_combine(const float* __restrict__ B,
                                                      const int* __restrict__ seg,
                                                      float* __restrict__ out,
                                                      int label, Kw kw) {
    const int v = swz(blockIdx.x) * 256 + threadIdx.x;
    const int x = v & 127;
    float g000 = 0, g001 = 0, g002 = 0, g010 = 0, g011 = 0,
          g020 = 0, g100 = 0, g101 = 0, g110 = 0, g200 = 0;
    for (int j = 0; j < KL; ++j) {
        int xx = x + j - R;
        if ((unsigned)xx < 128u) {
            int idx = v + (j - R);
            float b00 = B[idx],          b01 = B[NV + idx],     b02 = B[2 * NV + idx],
                  b10 = B[3 * NV + idx], b11 = B[4 * NV + idx], b20 = B[5 * NV + idx];
            float w0 = kw.k0[j], w1 = kw.k1[j], w2 = kw.k2[j];
            g000 = fmaf(w0, b00, g000);
            g001 = fmaf(w1, b00, g001);
            g002 = fmaf(w2, b00, g002);
            g010 = fmaf(w0, b01, g010);
            g011 = fmaf(w1, b01, g011);
            g020 = fmaf(w0, b02, g020);
            g100 = fmaf(w0, b10, g100);
            g101 = fmaf(w1, b10, g101);
            g110 = fmaf(w0, b11, g110);
            g200 = fmaf(w0, b20, g200);
        }
    }
    if (seg[v] == label) {
        float denom = (g000 > 0.f) ? g000 : 1.f;
        float inv = 1.f / denom;
        float p = g100 * inv, q = g010 * inv, s = g001 * inv;
        const float cs = 1.0f / 25.0f;   // 1/sigma^2
        float o[10];
        o[0] = 0.5f - 0.1f * p;          // 1/(2 sigma) = 0.1
        o[1] = 0.5f - 0.1f * q;
        o[2] = 0.5f - 0.1f * s;
        o[3] = (g200 * inv - p * p) * cs;
        o[4] = (g020 * inv - q * q) * cs;
        o[5] = (g002 * inv - s * s) * cs;
        o[6] = (g110 * inv - p * q) * cs;
        o[7] = (g011 * inv - q * s) * cs;
        o[8] = (g101 * inv - p * s) * cs;
        o[9] = g000;                     // mass
#pragma unroll
        for (int c = 0; c < 10; ++c) {
            float val = fminf(fmaxf(o[c], 0.f), 1.f);
            out[c * NV + v] = val;
        }
    }
}

extern "C" void kernel_launch(void* const* d_in, const int* in_sizes, int n_in,
                              void* d_out, int out_size, void* d_ws, size_t ws_size,
                              hipStream_t stream) {
    const int* seg = (const int*)d_in[0];
    // d_in[1] (coords) unused: math is translation-invariant.
    float* out = (float*)d_out;
    float* A = (float*)d_ws;                           // 3 volumes
    float* B = A + (size_t)3 * NV;                     // 6 volumes (9*8MB = 72MB)
    unsigned char* seg8 = (unsigned char*)(B + (size_t)6 * NV);
    const bool use8 = ws_size >= (size_t)9 * NV * sizeof(float) + NV;  // +2MB for seg8

    Kw kw;
    double g[KL], S = 0.0;
    for (int j = 0; j < KL; ++j) { double d = j - R; g[j] = exp(-0.5 * d * d / 25.0); S += g[j]; }
    for (int j = 0; j < KL; ++j) {
        double gn = g[j] / S, d = j - R;
        kw.k0[j] = (float)gn;
        kw.k1[j] = (float)(-d * gn);   // conv kernel k1 evaluated at (Z - t) = -d
        kw.k2[j] = (float)(d * d * gn);
    }

    hipMemsetAsync(d_out, 0, (size_t)out_size * sizeof(float), stream);

    dim3 grid(NV / 256), block(256);
    if (use8) seg_to_u8<<<dim3(NV / 1024), block, 0, stream>>>(seg, seg8);
    for (int label = 1; label <= 8; ++label) {
        if (use8) pass_z8<<<grid, block, 0, stream>>>(seg8, A, label, kw);
        else      pass_z32<<<grid, block, 0, stream>>>(seg, A, label, kw);
        pass_y<<<grid, block, 0, stream>>>(A, B, kw);
        pass_x_combine<<<grid, block, 0, stream>>>(B, seg, out, label, kw);
    }
}

// Round 3
// 794.308 us; speedup vs baseline: 2.0358x; 1.7168x over previous
//
#include <hip/hip_runtime.h>
#include <math.h>

// LSD (local shape descriptors), 128^3, 8 labels, sigma=5, truncate=3 -> 31-tap kernel.
//
// Algebra: for label mask m, define G_{abc} = (k_a *_z)(k_b *_y)(k_c *_x) m with
//   k0(u)=w(u), k1(u)=u w(u), k2(u)=u^2 w(u)  (w = normalized gaussian).
// At a voxel with mass=G000>0, p=G100/mass, q=G010/mass, s=G001/mass:
//   mean_offset = 0.5 - {p,q,s}/(2 sigma);  cov_ab = (G.. / mass - ..)/sigma^2.
// Translation-invariant: coords input not needed. Masks disjoint -> each voxel
// takes only its own label's descriptor.
//
// R1: XCD z-slab swizzle (measured 7.25x pass_y overfetch fixed; 174->~25 MB).
// R2 counters: pass_x 80us, VALUBusy 56%, HBM 12% -> VMEM-issue bound
//   (186 scalar loads/voxel). R3: register-tiled sliding-window conv:
//   each thread computes 4 consecutive outputs along the conv axis; loads
//   drop 31x -> ~8x per tap-window. pass_z/y: rolled j-loop with LDS-padded
//   weights (avoids dynamic kernarg indexing). pass_x: full unroll, float4
//   window in registers, exact tap bounds folded at compile time.

constexpr int NV = 128 * 128 * 128;
constexpr int SLICE = 128 * 128;
constexpr int R = 15;
constexpr int KL = 31;

struct Kw { float k0[KL]; float k1[KL]; float k2[KL]; };

__device__ __forceinline__ void fma4(float4& a, float w, const float4& b) {
    a.x = fmaf(w, b.x, a.x); a.y = fmaf(w, b.y, a.y);
    a.z = fmaf(w, b.z, a.z); a.w = fmaf(w, b.w, a.w);
}

__device__ __forceinline__ float4 load_mask4(const unsigned char* p, int lab) {
    unsigned int u = *(const unsigned int*)p;
    return make_float4(((u       ) & 255u) == (unsigned)lab ? 1.f : 0.f,
                       ((u >>  8 ) & 255u) == (unsigned)lab ? 1.f : 0.f,
                       ((u >> 16 ) & 255u) == (unsigned)lab ? 1.f : 0.f,
                       ((u >> 24 ) & 255u) == (unsigned)lab ? 1.f : 0.f);
}
__device__ __forceinline__ float4 load_mask4(const int* p, int lab) {
    int4 s = *(const int4*)p;
    return make_float4(s.x == lab ? 1.f : 0.f, s.y == lab ? 1.f : 0.f,
                       s.z == lab ? 1.f : 0.f, s.w == lab ? 1.f : 0.f);
}

// ---------------- pass_z: seg -> A[3] (z-conv), tile: 4x (vec) x 4z --------
template <typename ST>
__global__ __launch_bounds__(256) void pass_z_t(const ST* __restrict__ seg,
                                                float* __restrict__ A,
                                                int label, Kw kw) {
    __shared__ float kp[3][37];           // zero-padded: kp[c][i] = k_c[i-3]
    if (threadIdx.x == 0) {
#pragma unroll
        for (int i = 0; i < 37; ++i) {
            int j = i - 3; bool ok = (j >= 0) && (j < KL);
            kp[0][i] = ok ? kw.k0[j] : 0.f;
            kp[1][i] = ok ? kw.k1[j] : 0.f;
            kp[2][i] = ok ? kw.k2[j] : 0.f;
        }
    }
    __syncthreads();
    const int h = blockIdx.x, g = h & 7, l = h >> 3;       // 512 blocks
    const int tx = threadIdx.x & 31, ty = threadIdx.x >> 5;
    const int x0 = tx * 4;
    const int z0 = 16 * g + 4 * (l & 3);                   // XCD g owns z [16g,16g+16)
    const int y  = (l >> 2) * 8 + ty;

    float4 acc[4][3];
#pragma unroll
    for (int t = 0; t < 4; ++t)
#pragma unroll
        for (int c = 0; c < 3; ++c) acc[t][c] = make_float4(0.f, 0.f, 0.f, 0.f);

    for (int j = 0; j < 34; ++j) {                         // window: 4 outs + 30
        int zz = z0 + j - R;                               // uniform per wave
        float4 m = make_float4(0.f, 0.f, 0.f, 0.f);
        if ((unsigned)zz < 128u)
            m = load_mask4(seg + (zz * SLICE + y * 128 + x0), label);
#pragma unroll
        for (int t = 0; t < 4; ++t) {
            int i = j - t + 3;                             // padded weight index
            fma4(acc[t][0], kp[0][i], m);
            fma4(acc[t][1], kp[1][i], m);
            fma4(acc[t][2], kp[2][i], m);
        }
    }
#pragma unroll
    for (int t = 0; t < 4; ++t) {
        int base = (z0 + t) * SLICE + y * 128 + x0;
#pragma unroll
        for (int c = 0; c < 3; ++c)
            *(float4*)(A + (size_t)c * NV + base) = acc[t][c];
    }
}

// ---------------- pass_y: A[3] -> B[6] (y-conv), tile: 4x (vec) x 4y -------
__global__ __launch_bounds__(256) void pass_y(const float* __restrict__ A,
                                              float* __restrict__ B, Kw kw) {
    __shared__ float kp[3][37];
    if (threadIdx.x == 0) {
#pragma unroll
        for (int i = 0; i < 37; ++i) {
            int j = i - 3; bool ok = (j >= 0) && (j < KL);
            kp[0][i] = ok ? kw.k0[j] : 0.f;
            kp[1][i] = ok ? kw.k1[j] : 0.f;
            kp[2][i] = ok ? kw.k2[j] : 0.f;
        }
    }
    __syncthreads();
    const int h = blockIdx.x, g = h & 7, l = h >> 3;       // 512 blocks
    const int tx = threadIdx.x & 31, tz = threadIdx.x >> 5;
    const int x0 = tx * 4;
    const int z  = (2 * g + (l & 1)) * 8 + tz;             // z in [16g,16g+16)
    const int y0 = (l >> 1) * 4;
    const int zs = z * SLICE;

    float4 bacc[6][4];                                     // [ch][t]
#pragma unroll
    for (int c = 0; c < 6; ++c)
#pragma unroll
        for (int t = 0; t < 4; ++t) bacc[c][t] = make_float4(0.f, 0.f, 0.f, 0.f);

    for (int j = 0; j < 34; ++j) {
        int yy = y0 + j - R;                               // uniform per wave
        float4 a0 = make_float4(0.f, 0.f, 0.f, 0.f), a1 = a0, a2 = a0;
        if ((unsigned)yy < 128u) {
            int base = zs + yy * 128 + x0;
            a0 = *(const float4*)(A + base);
            a1 = *(const float4*)(A + NV + base);
            a2 = *(const float4*)(A + 2 * NV + base);
        }
#pragma unroll
        for (int t = 0; t < 4; ++t) {
            int i = j - t + 3;
            float w0 = kp[0][i], w1 = kp[1][i], w2 = kp[2][i];
            fma4(bacc[0][t], w0, a0);
            fma4(bacc[1][t], w1, a0);
            fma4(bacc[2][t], w2, a0);
            fma4(bacc[3][t], w0, a1);
            fma4(bacc[4][t], w1, a1);
            fma4(bacc[5][t], w0, a2);
        }
    }
#pragma unroll
    for (int t = 0; t < 4; ++t) {
        int base = zs + (y0 + t) * 128 + x0;
#pragma unroll
        for (int c = 0; c < 6; ++c)
            *(float4*)(B + (size_t)c * NV + base) = bacc[c][t];
    }
}

// ---------------- pass_x: B[6] -> out (x-conv + epilogue), tile 4x ---------
// Window of 36 floats (9 aligned float4) held in registers per channel.
template <int NO>
__device__ __forceinline__ void convx(const float* __restrict__ Brow, int x0,
                                      const Kw& kw, float o0[4], float o1[4],
                                      float o2[4]) {
    float W[36];
#pragma unroll
    for (int i = 0; i < 9; ++i) {
        int off = x0 - 16 + 4 * i;
        float4 w = ((unsigned)off < 128u) ? *(const float4*)(Brow + off)
                                          : make_float4(0.f, 0.f, 0.f, 0.f);
        W[4 * i] = w.x; W[4 * i + 1] = w.y; W[4 * i + 2] = w.z; W[4 * i + 3] = w.w;
    }
#pragma unroll
    for (int t = 0; t < 4; ++t) {
#pragma unroll
        for (int j = 0; j < KL; ++j) {                     // u = t+j+1 in [1,34]
            float wv = W[t + j + 1];
            o0[t] = fmaf(kw.k0[j], wv, o0[t]);
            if (NO > 1) o1[t] = fmaf(kw.k1[j], wv, o1[t]);
            if (NO > 2) o2[t] = fmaf(kw.k2[j], wv, o2[t]);
        }
    }
}

template <typename ST>
__global__ __launch_bounds__(256) void pass_x_t(const float* __restrict__ B,
                                                const ST* __restrict__ seg,
                                                float* __restrict__ out,
                                                int label, Kw kw) {
    const int h = blockIdx.x, g = h & 7, l = h >> 3;       // 2048 blocks
    const int tx = threadIdx.x & 31, tr = threadIdx.x >> 5;
    const int x0 = tx * 4;
    const int z  = 16 * g + (l >> 4);
    const int row = z * 128 + (l & 15) * 8 + tr;
    const int vrow = row * 128;

    float g000[4] = {0,0,0,0}, g001[4] = {0,0,0,0}, g002[4] = {0,0,0,0},
          g010[4] = {0,0,0,0}, g011[4] = {0,0,0,0}, g020[4] = {0,0,0,0},
          g100[4] = {0,0,0,0}, g101[4] = {0,0,0,0}, g110[4] = {0,0,0,0},
          g200[4] = {0,0,0,0};

    convx<3>(B + vrow,                     x0, kw, g000, g001, g002);
    convx<2>(B + (size_t)1 * NV + vrow,    x0, kw, g010, g011, g011);
    convx<1>(B + (size_t)2 * NV + vrow,    x0, kw, g020, g020, g020);
    convx<2>(B + (size_t)3 * NV + vrow,    x0, kw, g100, g101, g101);
    convx<1>(B + (size_t)4 * NV + vrow,    x0, kw, g110, g110, g110);
    convx<1>(B + (size_t)5 * NV + vrow,    x0, kw, g200, g200, g200);

#pragma unroll
    for (int t = 0; t < 4; ++t) {
        int v = vrow + x0 + t;
        if (seg[v] == (ST)label) {
            float mass = g000[t];
            float denom = (mass > 0.f) ? mass : 1.f;
            float inv = 1.f / denom;
            float p = g100[t] * inv, q = g010[t] * inv, s = g001[t] * inv;
            const float cs = 1.0f / 25.0f;                 // 1/sigma^2
            float o[10];
            o[0] = 0.5f - 0.1f * p;                        // 1/(2 sigma) = 0.1
            o[1] = 0.5f - 0.1f * q;
            o[2] = 0.5f - 0.1f * s;
            o[3] = (g200[t] * inv - p * p) * cs;
            o[4] = (g020[t] * inv - q * q) * cs;
            o[5] = (g002[t] * inv - s * s) * cs;
            o[6] = (g110[t] * inv - p * q) * cs;
            o[7] = (g011[t] * inv - q * s) * cs;
            o[8] = (g101[t] * inv - p * s) * cs;
            o[9] = mass;
#pragma unroll
            for (int c = 0; c < 10; ++c) {
                float val = fminf(fmaxf(o[c], 0.f), 1.f);
                out[(size_t)c * NV + v] = val;
            }
        }
    }
}

__global__ __launch_bounds__(256) void seg_to_u8(const int* __restrict__ seg,
                                                 unsigned char* __restrict__ seg8) {
    const int t = blockIdx.x * 256 + threadIdx.x;          // 2048 blocks
    const int4 s = ((const int4*)seg)[t];
    ((uchar4*)seg8)[t] = make_uchar4((unsigned char)s.x, (unsigned char)s.y,
                                     (unsigned char)s.z, (unsigned char)s.w);
}

extern "C" void kernel_launch(void* const* d_in, const int* in_sizes, int n_in,
                              void* d_out, int out_size, void* d_ws, size_t ws_size,
                              hipStream_t stream) {
    const int* seg = (const int*)d_in[0];
    // d_in[1] (coords) unused: math is translation-invariant.
    float* out = (float*)d_out;
    float* A = (float*)d_ws;                               // 3 volumes
    float* B = A + (size_t)3 * NV;                         // 6 volumes (72 MB)
    unsigned char* seg8 = (unsigned char*)(B + (size_t)6 * NV);
    const bool use8 = ws_size >= (size_t)9 * NV * sizeof(float) + NV;

    Kw kw;
    double gg[KL], S = 0.0;
    for (int j = 0; j < KL; ++j) { double d = j - R; gg[j] = exp(-0.5 * d * d / 25.0); S += gg[j]; }
    for (int j = 0; j < KL; ++j) {
        double gn = gg[j] / S, d = j - R;
        kw.k0[j] = (float)gn;
        kw.k1[j] = (float)(-d * gn);   // conv kernel k1 evaluated at (Z - t) = -d
        kw.k2[j] = (float)(d * d * gn);
    }

    hipMemsetAsync(d_out, 0, (size_t)out_size * sizeof(float), stream);

    dim3 block(256);
    if (use8) seg_to_u8<<<dim3(2048), block, 0, stream>>>(seg, seg8);
    for (int label = 1; label <= 8; ++label) {
        if (use8) pass_z_t<unsigned char><<<dim3(512), block, 0, stream>>>(seg8, A, label, kw);
        else      pass_z_t<int><<<dim3(512), block, 0, stream>>>(seg, A, label, kw);
        pass_y<<<dim3(512), block, 0, stream>>>(A, B, kw);
        if (use8) pass_x_t<unsigned char><<<dim3(2048), block, 0, stream>>>(B, seg8, out, label, kw);
        else      pass_x_t<int><<<dim3(2048), block, 0, stream>>>(B, seg, out, label, kw);
    }
}